// Round 17
// baseline (127.225 us; speedup 1.0000x reference)
//
#include <hip/hip_runtime.h>

// Problem constants: B=2, N=2048, C=1024, H=16, hd=64
// x:(2,2048,1024) f32; Wqkv:(1024,3072); Wproj:(1024,1024); bproj:(1024); q_scale,k_scale:(64)
// out:(2,2048,1024) f32

typedef _Float16 half_t;
typedef __attribute__((ext_vector_type(2))) __fp16 fp16x2;
typedef __attribute__((ext_vector_type(4))) _Float16 half4v;
typedef __attribute__((ext_vector_type(8))) _Float16 half8;
typedef __attribute__((ext_vector_type(4))) float f32x4;
typedef __attribute__((ext_vector_type(4))) unsigned uint4v;

#define DI __device__ __forceinline__

DI void gl_lds16(const void* g, void* l) {
    __builtin_amdgcn_global_load_lds((const __attribute__((address_space(1))) void*)g,
                                     (__attribute__((address_space(3))) void*)l, 16, 0, 0);
}

DI float exp2_fast(float x) {
    float r;
    asm("v_exp_f32 %0, %1" : "=v"(r) : "v"(x));
    return r;
}

// v_permlane32_swap_b32: a.rows[2,3] <-> b.rows[0,1] (rows = 16-lane groups)
DI void pl32_swap(unsigned& a, unsigned& b) {
    asm("v_permlane32_swap_b32 %0, %1" : "+v"(a), "+v"(b));
}
// v_permlane16_swap_b32: a.rows[1,3] <-> b.rows[0,2]
DI void pl16_swap(unsigned& a, unsigned& b) {
    asm("v_permlane16_swap_b32 %0, %1" : "+v"(a), "+v"(b));
}

DI unsigned pk_u32(float lo, float hi) {
    fp16x2 t = __builtin_amdgcn_cvt_pkrtz(lo, hi);
    return *(unsigned*)&t;
}

// ---------------- prep kernel (weights only; x-conversion fused into gemm_qkv) -----
// blocks [0,3072): Wqkv transpose->fp16 ; [3072,4096): Wproj transpose->fp16
__global__ void prep_all(const float* __restrict__ Wqkv, const float* __restrict__ Wproj,
                         half_t* __restrict__ wqt, half_t* __restrict__ wpt) {
    __shared__ float t[32][33];
    int bid = blockIdx.x;
    if (bid < 3072) {
        int i = bid;
        int c0 = (i % 96) * 32, r0 = (i / 96) * 32;
        int tx = threadIdx.x & 31, ty = threadIdx.x >> 5;
#pragma unroll
        for (int k = 0; k < 4; k++)
            t[ty + 8 * k][tx] = Wqkv[(size_t)(r0 + ty + 8 * k) * 3072 + c0 + tx];
        __syncthreads();
#pragma unroll
        for (int k = 0; k < 4; k++)
            wqt[(size_t)(c0 + ty + 8 * k) * 1024 + r0 + tx] = (half_t)t[tx][ty + 8 * k];
    } else {
        int i = bid - 3072;
        int c0 = (i % 32) * 32, r0 = (i / 32) * 32;
        int tx = threadIdx.x & 31, ty = threadIdx.x >> 5;
#pragma unroll
        for (int k = 0; k < 4; k++)
            t[ty + 8 * k][tx] = Wproj[(size_t)(r0 + ty + 8 * k) * 1024 + c0 + tx];
        __syncthreads();
#pragma unroll
        for (int k = 0; k < 4; k++)
            wpt[(size_t)(c0 + ty + 8 * k) * 1024 + r0 + tx] = (half_t)t[tx][ty + 8 * k];
    }
}

// ---------------- QKV GEMM: fp16, BK=32, dbuf, fused x-conversion + RMSNorm --------
// A staged DIRECTLY from f32 x (T14 reg-split): issue 2x(2 float4) loads right
// after the barrier, MFMAs hide the latency, cvt_pkrtz + ds_write_b128 to the
// swizzled slot just before the barrier. Write swizzle seg^((row>>1)&3) matches
// the read side (involution both sides). B stays global_load_lds from wqt.
// Same RTN cast as the old prep_x -> bit-identical numerics. 32KB LDS.
__global__ __launch_bounds__(256, 4) void gemm_qkv(
    const float* __restrict__ X, const half_t* __restrict__ Bt,
    const float* __restrict__ qs, const float* __restrict__ ks,
    half_t* __restrict__ qh, half_t* __restrict__ kh, half_t* __restrict__ vth) {
    const int K = 1024;
    __shared__ __align__(16) half_t Al[2][128 * 32];
    __shared__ __align__(16) half_t Bl[2][128 * 32];
    int tid = threadIdx.x;
    int w = tid >> 6, l = tid & 63;
    int wr = w >> 1, wc = w & 1;
    int g = l >> 4, r = l & 15;
    int m0 = blockIdx.x * 128, n0 = blockIdx.y * 128;
    f32x4 acc[4][4] = {};

    // A staging coords (fixed per thread): 512 8-elem chunks, 2 per thread
    int arow[2], alc[2];
    const float* asrc[2];
#pragma unroll
    for (int p = 0; p < 2; p++) {
        int ci = p * 256 + tid;
        arow[p] = ci >> 2;
        int seg = ci & 3;
        alc[p] = seg ^ ((arow[p] >> 1) & 3);  // phys chunk for this source seg
        asrc[p] = X + (size_t)(m0 + arow[p]) * K + seg * 8;  // advances by 32/tile
    }

#define STAGE_B(kt, buf)                                                          \
    {                                                                             \
        _Pragma("unroll")                                                         \
        for (int p = 0; p < 2; p++) {                                             \
            int ci = p * 256 + tid;                                               \
            int row = ci >> 2, c = ci & 3, lc = c ^ ((row >> 1) & 3);             \
            gl_lds16(Bt + (size_t)(n0 + row) * K + (kt) * 32 + lc * 8,            \
                     &Bl[buf][0] + ci * 8);                                       \
        }                                                                         \
    }

#define LOAD_A(a0, a1)                                                            \
    {                                                                             \
        _Pragma("unroll")                                                         \
        for (int p = 0; p < 2; p++) {                                             \
            a0[p] = *(const f32x4*)(asrc[p]);                                     \
            a1[p] = *(const f32x4*)(asrc[p] + 4);                                 \
            asrc[p] += 32;                                                        \
        }                                                                         \
    }

#define WRITE_A(a0, a1, buf)                                                      \
    {                                                                             \
        _Pragma("unroll")                                                         \
        for (int p = 0; p < 2; p++) {                                             \
            uint4v hv;                                                            \
            hv[0] = pk_u32(a0[p][0], a0[p][1]);                                   \
            hv[1] = pk_u32(a0[p][2], a0[p][3]);                                   \
            hv[2] = pk_u32(a1[p][0], a1[p][1]);                                   \
            hv[3] = pk_u32(a1[p][2], a1[p][3]);                                   \
            *(uint4v*)(&Al[buf][0] + arow[p] * 32 + alc[p] * 8) = hv;             \
        }                                                                         \
    }

    // prologue: stage tile 0 (A via regs, B via global_load_lds)
    {
        f32x4 a0[2], a1[2];
        LOAD_A(a0, a1);
        STAGE_B(0, 0);
        WRITE_A(a0, a1, 0);
    }
    __syncthreads();
    int cur = 0;
    for (int kt = 0; kt < 32; kt++) {
        f32x4 a0[2], a1[2];
        if (kt < 31) {
            LOAD_A(a0, a1);          // issue f32 loads early (latency hides under MFMAs)
            STAGE_B(kt + 1, cur ^ 1);
        }
        half8 af[4], bf[4];
#pragma unroll
        for (int i = 0; i < 4; i++) {
            int row = wr * 64 + i * 16 + r;
            af[i] = *(const half8*)(&Al[cur][0] + row * 32 + ((g ^ ((row >> 1) & 3)) << 3));
            int rowb = wc * 64 + i * 16 + r;
            bf[i] = *(const half8*)(&Bl[cur][0] + rowb * 32 + ((g ^ ((rowb >> 1) & 3)) << 3));
        }
#pragma unroll
        for (int i = 0; i < 4; i++)
#pragma unroll
            for (int j = 0; j < 4; j++)
                acc[i][j] = __builtin_amdgcn_mfma_f32_16x16x32_f16(af[i], bf[j], acc[i][j], 0, 0, 0);
        if (kt < 31) WRITE_A(a0, a1, cur ^ 1);  // vmcnt wait + cvt + ds_write, then barrier
        __syncthreads();
        cur ^= 1;
    }

    int tsec = n0 >> 10;  // 0=q, 1=k, 2=v (uniform per block)
    if (tsec == 2) {
#pragma unroll
        for (int i = 0; i < 4; i++)
#pragma unroll
            for (int j = 0; j < 4; j++) {
                int gcol = n0 + wc * 64 + j * 16 + r;
                int h = (gcol >> 6) & 15;
                int f = gcol & 63;
                int growb = m0 + wr * 64 + i * 16 + g * 4;
                int b = growb >> 11;
                int n = growb & 2047;
                half4v pv;
#pragma unroll
                for (int rr = 0; rr < 4; rr++) pv[rr] = (half_t)acc[i][j][rr];
                *(half4v*)(vth + ((size_t)(b * 16 + h) * 64 + f) * 2048 + n) = pv;
            }
    } else {
        const float* sc = (tsec == 0) ? qs : ks;
        half_t* dst = (tsec == 0) ? qh : kh;
        float extra = (tsec == 0) ? (0.125f * 1.44269504f) : 1.0f;  // fold hd^-0.5*log2e into q
        float scv[4];
#pragma unroll
        for (int j = 0; j < 4; j++) scv[j] = sc[j * 16 + r];
#pragma unroll
        for (int i = 0; i < 4; i++)
#pragma unroll
            for (int rr = 0; rr < 4; rr++) {
                float ss = 0.f;
#pragma unroll
                for (int j = 0; j < 4; j++) ss += acc[i][j][rr] * acc[i][j][rr];
#pragma unroll
                for (int d = 1; d < 16; d <<= 1) ss += __shfl_xor(ss, d, 64);
                float inv = extra / (sqrtf(ss) * 0.125f + 1e-8f);  // rms = ||row||/8
                int grow = m0 + wr * 64 + i * 16 + g * 4 + rr;
                int b = grow >> 11;
                int n = grow & 2047;
#pragma unroll
                for (int j = 0; j < 4; j++) {
                    int gcol = n0 + wc * 64 + j * 16 + r;
                    int h = (gcol >> 6) & 15;
                    int f = gcol & 63;
                    dst[((size_t)(b * 16 + h) * 2048 + n) * 64 + f] =
                        (half_t)(acc[i][j][rr] * inv * scv[j]);
                }
            }
    }
}

// ---------------- flash attention: IN-BLOCK kv-split-2, 32 waves/CU ----------------
// EXACT R13/R15/R16 kernel (proven pass, 56.5us). Do NOT change lsum mechanics
// (R6 no-max and R14 ones-MFMA both failed ~5e-2).
__global__ __launch_bounds__(512, 8) void attn(
    const half_t* __restrict__ qh, const half_t* __restrict__ kh,
    const half_t* __restrict__ vth, half_t* __restrict__ aoh) {
    int bh = blockIdx.y;
    int q0 = blockIdx.x * 64;
    int tid = threadIdx.x, w = tid >> 6, l = tid & 63, g = l >> 4, r = l & 15;
    int hf = w >> 2, qs = w & 3, lt = tid & 255;

    const half_t* Qp = qh + (size_t)bh * 2048 * 64;
    const half_t* Kp = kh + (size_t)bh * 2048 * 64 + (size_t)hf * 1024 * 64;
    const half_t* Vp = vth + (size_t)bh * 64 * 2048 + hf * 1024;  // (feat, n)

    __shared__ __align__(16) char smem[32768];
    half_t* Kb[2] = {(half_t*)(smem + hf * 8192), (half_t*)(smem + hf * 8192 + 4096)};
    half_t* Vb[2] = {(half_t*)(smem + 16384 + hf * 8192), (half_t*)(smem + 16384 + hf * 8192 + 4096)};

    int krow = lt >> 3, kc = lt & 7, klc = kc ^ (krow & 7);
    const half_t* kst = Kp + (size_t)krow * 64 + klc * 8;
    int vrow = lt >> 2, vc = lt & 3, vlc = vc ^ ((vrow >> 1) & 3);
    const half_t* vst = Vp + (size_t)vrow * 2048 + vlc * 8;

    int koff[4], voff[4];
#pragma unroll
    for (int ks = 0; ks < 2; ks++)
#pragma unroll
        for (int tt = 0; tt < 2; tt++) {
            int row = tt * 16 + r;
            koff[ks * 2 + tt] = row * 64 + (((ks * 4 + g) ^ (row & 7)) << 3);
        }
#pragma unroll
    for (int cf = 0; cf < 4; cf++) {
        int row = cf * 16 + r;
        voff[cf] = row * 32 + ((g ^ ((row >> 1) & 3)) << 3);
    }

    half8 qf[2];
#pragma unroll
    for (int ks = 0; ks < 2; ks++)
        qf[ks] = *(const half8*)(Qp + (size_t)(q0 + qs * 16 + r) * 64 + ks * 32 + g * 8);

    f32x4 o[4] = {};
    float m = -1e30f, lsum = 0.f;

    gl_lds16(kst, Kb[0] + lt * 8);
    gl_lds16(vst, Vb[0] + lt * 8);
    __syncthreads();

#define ATTN_TILE(BUF, T)                                                          \
    {                                                                              \
        if ((T) < 31) {                                                            \
            gl_lds16(kst + ((T) + 1) * 2048, Kb[(BUF) ^ 1] + lt * 8);              \
            gl_lds16(vst + ((T) + 1) * 32, Vb[(BUF) ^ 1] + lt * 8);                \
        }                                                                          \
        const half_t* Kc = Kb[BUF];                                                \
        const half_t* Vc = Vb[BUF];                                                \
        f32x4 s[2] = {};                                                           \
        _Pragma("unroll")                                                          \
        for (int ks = 0; ks < 2; ks++)                                             \
            _Pragma("unroll")                                                      \
            for (int tt = 0; tt < 2; tt++) {                                       \
                half8 kf = *(const half8*)(Kc + koff[ks * 2 + tt]);                \
                s[tt] = __builtin_amdgcn_mfma_f32_16x16x32_f16(kf, qf[ks], s[tt], 0, 0, 0); \
            }                                                                      \
        float thr = m + 11.0f;                                                     \
        bool ok = true;                                                            \
        _Pragma("unroll")                                                          \
        for (int tt = 0; tt < 2; tt++)                                             \
            _Pragma("unroll")                                                      \
            for (int e = 0; e < 4; e++) ok = ok && (s[tt][e] <= thr);              \
        if (!__all(ok)) {                                                          \
            float mx = fmaxf(fmaxf(s[0][0], s[0][1]), fmaxf(s[0][2], s[0][3]));    \
            mx = fmaxf(mx, fmaxf(fmaxf(s[1][0], s[1][1]), fmaxf(s[1][2], s[1][3]))); \
            mx = fmaxf(mx, __shfl_xor(mx, 16, 64));                                \
            mx = fmaxf(mx, __shfl_xor(mx, 32, 64));                                \
            float mn = fmaxf(m, mx);                                               \
            float fac = exp2_fast(m - mn);                                         \
            lsum *= fac;                                                           \
            _Pragma("unroll")                                                      \
            for (int cf = 0; cf < 4; cf++) {                                       \
                o[cf][0] *= fac; o[cf][1] *= fac; o[cf][2] *= fac; o[cf][3] *= fac; \
            }                                                                      \
            m = mn;                                                                \
        }                                                                          \
        _Pragma("unroll")                                                          \
        for (int tt = 0; tt < 2; tt++)                                             \
            _Pragma("unroll")                                                      \
            for (int e = 0; e < 4; e++) {                                          \
                float p = exp2_fast(s[tt][e] - m);                                 \
                s[tt][e] = p;                                                      \
                lsum += p;                                                         \
            }                                                                      \
        unsigned b0 = pk_u32(s[0][0], s[0][1]);                                    \
        unsigned b1 = pk_u32(s[0][2], s[0][3]);                                    \
        unsigned b2 = pk_u32(s[1][0], s[1][1]);                                    \
        unsigned b3 = pk_u32(s[1][2], s[1][3]);                                    \
        pl32_swap(b0, b2); pl16_swap(b0, b2);                                      \
        pl32_swap(b1, b3); pl16_swap(b1, b3);                                      \
        uint4v pw; pw[0] = b0; pw[1] = b1; pw[2] = b2; pw[3] = b3;                 \
        half8 pf = *(half8*)&pw;                                                   \
        _Pragma("unroll")                                                          \
        for (int cf = 0; cf < 4; cf++) {                                           \
            half8 vf = *(const half8*)(Vc + voff[cf]);                             \
            o[cf] = __builtin_amdgcn_mfma_f32_16x16x32_f16(vf, pf, o[cf], 0, 0, 0); \
        }                                                                          \
        __syncthreads();                                                           \
    }

    for (int t = 0; t < 32; t += 2) {
        ATTN_TILE(0, t);
        ATTN_TILE(1, t + 1);
    }

    lsum += __shfl_xor(lsum, 16, 64);
    lsum += __shfl_xor(lsum, 32, 64);

    float* mo = (float*)smem;             // [64 q][68] padded f32
    float* mml = (float*)(smem + 17408);  // [64 q][2] (m, ls)
    int q2 = qs * 16 + r;
    if (hf) {
#pragma unroll
        for (int cf = 0; cf < 4; cf++)
            *(f32x4*)(mo + q2 * 68 + cf * 16 + g * 4) = o[cf];
        if (l < 16) {
            mml[q2 * 2] = m;
            mml[q2 * 2 + 1] = lsum;
        }
    }
    __syncthreads();
    if (!hf) {
        float m1 = mml[q2 * 2], ls1 = mml[q2 * 2 + 1];
        float M = fmaxf(m, m1);
        float w0 = exp2_fast(m - M), w1 = exp2_fast(m1 - M);
        float inv = 1.0f / (w0 * lsum + w1 * ls1);
        w0 *= inv; w1 *= inv;
        int n = q0 + q2;
        int b = bh >> 4, h = bh & 15;
#pragma unroll
        for (int cf = 0; cf < 4; cf++) {
            f32x4 o1 = *(const f32x4*)(mo + q2 * 68 + cf * 16 + g * 4);
            half4v ov;
#pragma unroll
            for (int e = 0; e < 4; e++) ov[e] = (half_t)(o[cf][e] * w0 + o1[e] * w1);
            *(half4v*)(aoh + ((size_t)b * 2048 + n) * 1024 + h * 64 + cf * 16 + g * 4) = ov;
        }
    }
}

// ---------------- proj GEMM: 64x128 tile, BK=32, dbuf, + bias, f32 out -------------
// PROVEN R16: grid (64,8)=512 blocks -> 2 blocks/CU (8 waves/CU), 24KB LDS.
__global__ __launch_bounds__(256, 4) void gemm_proj(
    const half_t* __restrict__ A, const half_t* __restrict__ Bt,
    const float* __restrict__ bias, float* __restrict__ out) {
    const int K = 1024;
    __shared__ __align__(16) half_t Al[2][64 * 32];
    __shared__ __align__(16) half_t Bl[2][128 * 32];
    int tid = threadIdx.x, w = tid >> 6, l = tid & 63;
    int wr = w >> 1, wc = w & 1, g = l >> 4, r = l & 15;
    int m0 = blockIdx.x * 64, n0 = blockIdx.y * 128;
    f32x4 acc[2][4] = {};

#define STAGE_PROJ(kt, buf)                                                       \
    {                                                                             \
        {                                                                         \
            int ci = tid;                                                         \
            int row = ci >> 2, c = ci & 3, lc = c ^ ((row >> 1) & 3);             \
            gl_lds16(A + (size_t)(m0 + row) * K + (kt) * 32 + lc * 8,             \
                     &Al[buf][0] + ci * 8);                                       \
        }                                                                         \
        _Pragma("unroll")                                                         \
        for (int p = 0; p < 2; p++) {                                             \
            int ci = p * 256 + tid;                                               \
            int row = ci >> 2, c = ci & 3, lc = c ^ ((row >> 1) & 3);             \
            gl_lds16(Bt + (size_t)(n0 + row) * K + (kt) * 32 + lc * 8,            \
                     &Bl[buf][0] + ci * 8);                                       \
        }                                                                         \
    }

    STAGE_PROJ(0, 0);
    __syncthreads();
    int cur = 0;
    for (int kt = 0; kt < 32; kt++) {
        if (kt < 31) STAGE_PROJ(kt + 1, cur ^ 1);
        half8 af[2], bf[4];
#pragma unroll
        for (int i = 0; i < 2; i++) {
            int row = wr * 32 + i * 16 + r;
            af[i] = *(const half8*)(&Al[cur][0] + row * 32 + ((g ^ ((row >> 1) & 3)) << 3));
        }
#pragma unroll
        for (int j = 0; j < 4; j++) {
            int rowb = wc * 64 + j * 16 + r;
            bf[j] = *(const half8*)(&Bl[cur][0] + rowb * 32 + ((g ^ ((rowb >> 1) & 3)) << 3));
        }
#pragma unroll
        for (int i = 0; i < 2; i++)
#pragma unroll
            for (int j = 0; j < 4; j++)
                acc[i][j] = __builtin_amdgcn_mfma_f32_16x16x32_f16(af[i], bf[j], acc[i][j], 0, 0, 0);
        __syncthreads();
        cur ^= 1;
    }

#pragma unroll
    for (int i = 0; i < 2; i++)
#pragma unroll
        for (int j = 0; j < 4; j++) {
            int gcol = n0 + wc * 64 + j * 16 + r;
            float bv = bias[gcol];
#pragma unroll
            for (int rr = 0; rr < 4; rr++) {
                int grow = m0 + wr * 32 + i * 16 + g * 4 + rr;
                out[(size_t)grow * 1024 + gcol] = acc[i][j][rr] + bv;
            }
        }
}

// ---------------- launch ----------------
extern "C" void kernel_launch(void* const* d_in, const int* in_sizes, int n_in,
                              void* d_out, int out_size, void* d_ws, size_t ws_size,
                              hipStream_t stream) {
    const float* x = (const float*)d_in[0];
    const float* Wqkv = (const float*)d_in[1];
    const float* Wproj = (const float*)d_in[2];
    const float* bproj = (const float*)d_in[3];
    const float* qscale = (const float*)d_in[4];
    const float* kscale = (const float*)d_in[5];
    float* out = (float*)d_out;

    char* ws = (char*)d_ws;
    half_t* wqt = (half_t*)(ws + 8388608);   //  6.0 MB (3072 x 1024 fp16, transposed)
    half_t* wpt = (half_t*)(ws + 14680064);  //  2.0 MB (1024 x 1024 fp16, transposed)
    half_t* qh  = (half_t*)(ws + 16777216);  //  8.0 MB (b,h,n,f)
    half_t* kh  = (half_t*)(ws + 25165824);  //  8.0 MB (b,h,n,f)
    half_t* vth = (half_t*)(ws + 33554432);  //  8.0 MB (b,h,f,n)
    half_t* aoh = (half_t*)(ws + 41943040);  //  8.0 MB (b,n,c)

    prep_all<<<4096, 256, 0, stream>>>(Wqkv, Wproj, wqt, wpt);
    gemm_qkv<<<dim3(32, 24), 256, 0, stream>>>(x, wqt, qscale, kscale, qh, kh, vth);
    attn<<<dim3(32, 32), 512, 0, stream>>>(qh, kh, vth, aoh);
    gemm_proj<<<dim3(64, 8), 256, 0, stream>>>(aoh, wpt, bproj, out);
}

// Round 18
// 123.641 us; speedup vs baseline: 1.0290x; 1.0290x over previous
//
#include <hip/hip_runtime.h>

// Problem constants: B=2, N=2048, C=1024, H=16, hd=64
// x:(2,2048,1024) f32; Wqkv:(1024,3072); Wproj:(1024,1024); bproj:(1024); q_scale,k_scale:(64)
// out:(2,2048,1024) f32

typedef _Float16 half_t;
typedef __attribute__((ext_vector_type(2))) __fp16 fp16x2;
typedef __attribute__((ext_vector_type(4))) _Float16 half4v;
typedef __attribute__((ext_vector_type(8))) _Float16 half8;
typedef __attribute__((ext_vector_type(4))) float f32x4;
typedef __attribute__((ext_vector_type(4))) unsigned uint4v;

#define DI __device__ __forceinline__

DI void gl_lds16(const void* g, void* l) {
    __builtin_amdgcn_global_load_lds((const __attribute__((address_space(1))) void*)g,
                                     (__attribute__((address_space(3))) void*)l, 16, 0, 0);
}

DI float exp2_fast(float x) {
    float r;
    asm("v_exp_f32 %0, %1" : "=v"(r) : "v"(x));
    return r;
}

// v_permlane32_swap_b32: a.rows[2,3] <-> b.rows[0,1] (rows = 16-lane groups)
DI void pl32_swap(unsigned& a, unsigned& b) {
    asm("v_permlane32_swap_b32 %0, %1" : "+v"(a), "+v"(b));
}
// v_permlane16_swap_b32: a.rows[1,3] <-> b.rows[0,2]
DI void pl16_swap(unsigned& a, unsigned& b) {
    asm("v_permlane16_swap_b32 %0, %1" : "+v"(a), "+v"(b));
}

DI unsigned pk_u32(float lo, float hi) {
    fp16x2 t = __builtin_amdgcn_cvt_pkrtz(lo, hi);
    return *(unsigned*)&t;
}

// ---------------- merged prep kernel ----------------
// blocks [0,4096): x f32->fp16 ; [4096,7168): Wqkv transpose->fp16 ; [7168,8192): Wproj
// (R17's fused-x variant regressed: reg-staged A cost > prep_x savings. Keep separate.)
__global__ void prep_all(const float* __restrict__ x, const float* __restrict__ Wqkv,
                         const float* __restrict__ Wproj, half_t* __restrict__ xh,
                         half_t* __restrict__ wqt, half_t* __restrict__ wpt) {
    __shared__ float t[32][33];
    int bid = blockIdx.x;
    if (bid < 4096) {
        int i = (bid * 256 + threadIdx.x) * 4;
        float4 v = *(const float4*)(x + i);
        half4v o;
        o[0] = (half_t)v.x; o[1] = (half_t)v.y; o[2] = (half_t)v.z; o[3] = (half_t)v.w;
        *(half4v*)(xh + i) = o;
    } else if (bid < 4096 + 3072) {
        int i = bid - 4096;
        int c0 = (i % 96) * 32, r0 = (i / 96) * 32;
        int tx = threadIdx.x & 31, ty = threadIdx.x >> 5;
#pragma unroll
        for (int k = 0; k < 4; k++)
            t[ty + 8 * k][tx] = Wqkv[(size_t)(r0 + ty + 8 * k) * 3072 + c0 + tx];
        __syncthreads();
#pragma unroll
        for (int k = 0; k < 4; k++)
            wqt[(size_t)(c0 + ty + 8 * k) * 1024 + r0 + tx] = (half_t)t[tx][ty + 8 * k];
    } else {
        int i = bid - 4096 - 3072;
        int c0 = (i % 32) * 32, r0 = (i / 32) * 32;
        int tx = threadIdx.x & 31, ty = threadIdx.x >> 5;
#pragma unroll
        for (int k = 0; k < 4; k++)
            t[ty + 8 * k][tx] = Wproj[(size_t)(r0 + ty + 8 * k) * 1024 + c0 + tx];
        __syncthreads();
#pragma unroll
        for (int k = 0; k < 4; k++)
            wpt[(size_t)(c0 + ty + 8 * k) * 1024 + r0 + tx] = (half_t)t[tx][ty + 8 * k];
    }
}

// ---------------- QKV GEMM: fp16, BK=32, dbuf LDS (32KB -> ~5 blocks/CU) ------------
// PROVEN R15/R16. Rows are 4 chunks of 16B; stage/read swizzle c^((row>>1)&3)
// (XOR involution both sides); read = 2-way bank alias (free).
// Fused RMSNorm epilogue (q/k from f32 acc; v stored transposed).
__global__ __launch_bounds__(256, 4) void gemm_qkv(
    const half_t* __restrict__ A, const half_t* __restrict__ Bt,
    const float* __restrict__ qs, const float* __restrict__ ks,
    half_t* __restrict__ qh, half_t* __restrict__ kh, half_t* __restrict__ vth) {
    const int K = 1024;
    __shared__ __align__(16) half_t Al[2][128 * 32];
    __shared__ __align__(16) half_t Bl[2][128 * 32];
    int tid = threadIdx.x;
    int w = tid >> 6, l = tid & 63;
    int wr = w >> 1, wc = w & 1;
    int g = l >> 4, r = l & 15;
    int m0 = blockIdx.x * 128, n0 = blockIdx.y * 128;
    f32x4 acc[4][4] = {};

#define STAGE_QKV(kt, buf)                                                        \
    {                                                                             \
        _Pragma("unroll")                                                         \
        for (int p = 0; p < 2; p++) {                                             \
            int ci = p * 256 + tid;                                               \
            int row = ci >> 2, c = ci & 3, lc = c ^ ((row >> 1) & 3);             \
            gl_lds16(A + (size_t)(m0 + row) * K + (kt) * 32 + lc * 8,             \
                     &Al[buf][0] + ci * 8);                                       \
            gl_lds16(Bt + (size_t)(n0 + row) * K + (kt) * 32 + lc * 8,            \
                     &Bl[buf][0] + ci * 8);                                       \
        }                                                                         \
    }

    STAGE_QKV(0, 0);
    __syncthreads();
    int cur = 0;
    for (int kt = 0; kt < 32; kt++) {
        if (kt < 31) STAGE_QKV(kt + 1, cur ^ 1);
        half8 af[4], bf[4];
#pragma unroll
        for (int i = 0; i < 4; i++) {
            int row = wr * 64 + i * 16 + r;
            af[i] = *(const half8*)(&Al[cur][0] + row * 32 + ((g ^ ((row >> 1) & 3)) << 3));
            int rowb = wc * 64 + i * 16 + r;
            bf[i] = *(const half8*)(&Bl[cur][0] + rowb * 32 + ((g ^ ((rowb >> 1) & 3)) << 3));
        }
#pragma unroll
        for (int i = 0; i < 4; i++)
#pragma unroll
            for (int j = 0; j < 4; j++)
                acc[i][j] = __builtin_amdgcn_mfma_f32_16x16x32_f16(af[i], bf[j], acc[i][j], 0, 0, 0);
        __syncthreads();
        cur ^= 1;
    }

    int tsec = n0 >> 10;  // 0=q, 1=k, 2=v (uniform per block)
    if (tsec == 2) {
#pragma unroll
        for (int i = 0; i < 4; i++)
#pragma unroll
            for (int j = 0; j < 4; j++) {
                int gcol = n0 + wc * 64 + j * 16 + r;
                int h = (gcol >> 6) & 15;
                int f = gcol & 63;
                int growb = m0 + wr * 64 + i * 16 + g * 4;
                int b = growb >> 11;
                int n = growb & 2047;
                half4v pv;
#pragma unroll
                for (int rr = 0; rr < 4; rr++) pv[rr] = (half_t)acc[i][j][rr];
                *(half4v*)(vth + ((size_t)(b * 16 + h) * 64 + f) * 2048 + n) = pv;
            }
    } else {
        const float* sc = (tsec == 0) ? qs : ks;
        half_t* dst = (tsec == 0) ? qh : kh;
        float extra = (tsec == 0) ? (0.125f * 1.44269504f) : 1.0f;  // fold hd^-0.5*log2e into q
        float scv[4];
#pragma unroll
        for (int j = 0; j < 4; j++) scv[j] = sc[j * 16 + r];
#pragma unroll
        for (int i = 0; i < 4; i++)
#pragma unroll
            for (int rr = 0; rr < 4; rr++) {
                float ss = 0.f;
#pragma unroll
                for (int j = 0; j < 4; j++) ss += acc[i][j][rr] * acc[i][j][rr];
#pragma unroll
                for (int d = 1; d < 16; d <<= 1) ss += __shfl_xor(ss, d, 64);
                float inv = extra / (sqrtf(ss) * 0.125f + 1e-8f);  // rms = ||row||/8
                int grow = m0 + wr * 64 + i * 16 + g * 4 + rr;
                int b = grow >> 11;
                int n = grow & 2047;
#pragma unroll
                for (int j = 0; j < 4; j++) {
                    int gcol = n0 + wc * 64 + j * 16 + r;
                    int h = (gcol >> 6) & 15;
                    int f = gcol & 63;
                    dst[((size_t)(b * 16 + h) * 2048 + n) * 64 + f] =
                        (half_t)(acc[i][j][rr] * inv * scv[j]);
                }
            }
    }
}

// ---------------- flash attention: IN-BLOCK kv-split-2, 32 waves/CU ----------------
// EXACT R13/R15/R16 kernel (proven pass, 56.5us). Do NOT change lsum mechanics
// (R6 no-max and R14 ones-MFMA both failed ~5e-2).
__global__ __launch_bounds__(512, 8) void attn(
    const half_t* __restrict__ qh, const half_t* __restrict__ kh,
    const half_t* __restrict__ vth, half_t* __restrict__ aoh) {
    int bh = blockIdx.y;
    int q0 = blockIdx.x * 64;
    int tid = threadIdx.x, w = tid >> 6, l = tid & 63, g = l >> 4, r = l & 15;
    int hf = w >> 2, qs = w & 3, lt = tid & 255;

    const half_t* Qp = qh + (size_t)bh * 2048 * 64;
    const half_t* Kp = kh + (size_t)bh * 2048 * 64 + (size_t)hf * 1024 * 64;
    const half_t* Vp = vth + (size_t)bh * 64 * 2048 + hf * 1024;  // (feat, n)

    __shared__ __align__(16) char smem[32768];
    half_t* Kb[2] = {(half_t*)(smem + hf * 8192), (half_t*)(smem + hf * 8192 + 4096)};
    half_t* Vb[2] = {(half_t*)(smem + 16384 + hf * 8192), (half_t*)(smem + 16384 + hf * 8192 + 4096)};

    int krow = lt >> 3, kc = lt & 7, klc = kc ^ (krow & 7);
    const half_t* kst = Kp + (size_t)krow * 64 + klc * 8;
    int vrow = lt >> 2, vc = lt & 3, vlc = vc ^ ((vrow >> 1) & 3);
    const half_t* vst = Vp + (size_t)vrow * 2048 + vlc * 8;

    int koff[4], voff[4];
#pragma unroll
    for (int ks = 0; ks < 2; ks++)
#pragma unroll
        for (int tt = 0; tt < 2; tt++) {
            int row = tt * 16 + r;
            koff[ks * 2 + tt] = row * 64 + (((ks * 4 + g) ^ (row & 7)) << 3);
        }
#pragma unroll
    for (int cf = 0; cf < 4; cf++) {
        int row = cf * 16 + r;
        voff[cf] = row * 32 + ((g ^ ((row >> 1) & 3)) << 3);
    }

    half8 qf[2];
#pragma unroll
    for (int ks = 0; ks < 2; ks++)
        qf[ks] = *(const half8*)(Qp + (size_t)(q0 + qs * 16 + r) * 64 + ks * 32 + g * 8);

    f32x4 o[4] = {};
    float m = -1e30f, lsum = 0.f;

    gl_lds16(kst, Kb[0] + lt * 8);
    gl_lds16(vst, Vb[0] + lt * 8);
    __syncthreads();

#define ATTN_TILE(BUF, T)                                                          \
    {                                                                              \
        if ((T) < 31) {                                                            \
            gl_lds16(kst + ((T) + 1) * 2048, Kb[(BUF) ^ 1] + lt * 8);              \
            gl_lds16(vst + ((T) + 1) * 32, Vb[(BUF) ^ 1] + lt * 8);                \
        }                                                                          \
        const half_t* Kc = Kb[BUF];                                                \
        const half_t* Vc = Vb[BUF];                                                \
        f32x4 s[2] = {};                                                           \
        _Pragma("unroll")                                                          \
        for (int ks = 0; ks < 2; ks++)                                             \
            _Pragma("unroll")                                                      \
            for (int tt = 0; tt < 2; tt++) {                                       \
                half8 kf = *(const half8*)(Kc + koff[ks * 2 + tt]);                \
                s[tt] = __builtin_amdgcn_mfma_f32_16x16x32_f16(kf, qf[ks], s[tt], 0, 0, 0); \
            }                                                                      \
        float thr = m + 11.0f;                                                     \
        bool ok = true;                                                            \
        _Pragma("unroll")                                                          \
        for (int tt = 0; tt < 2; tt++)                                             \
            _Pragma("unroll")                                                      \
            for (int e = 0; e < 4; e++) ok = ok && (s[tt][e] <= thr);              \
        if (!__all(ok)) {                                                          \
            float mx = fmaxf(fmaxf(s[0][0], s[0][1]), fmaxf(s[0][2], s[0][3]));    \
            mx = fmaxf(mx, fmaxf(fmaxf(s[1][0], s[1][1]), fmaxf(s[1][2], s[1][3]))); \
            mx = fmaxf(mx, __shfl_xor(mx, 16, 64));                                \
            mx = fmaxf(mx, __shfl_xor(mx, 32, 64));                                \
            float mn = fmaxf(m, mx);                                               \
            float fac = exp2_fast(m - mn);                                         \
            lsum *= fac;                                                           \
            _Pragma("unroll")                                                      \
            for (int cf = 0; cf < 4; cf++) {                                       \
                o[cf][0] *= fac; o[cf][1] *= fac; o[cf][2] *= fac; o[cf][3] *= fac; \
            }                                                                      \
            m = mn;                                                                \
        }                                                                          \
        _Pragma("unroll")                                                          \
        for (int tt = 0; tt < 2; tt++)                                             \
            _Pragma("unroll")                                                      \
            for (int e = 0; e < 4; e++) {                                          \
                float p = exp2_fast(s[tt][e] - m);                                 \
                s[tt][e] = p;                                                      \
                lsum += p;                                                         \
            }                                                                      \
        unsigned b0 = pk_u32(s[0][0], s[0][1]);                                    \
        unsigned b1 = pk_u32(s[0][2], s[0][3]);                                    \
        unsigned b2 = pk_u32(s[1][0], s[1][1]);                                    \
        unsigned b3 = pk_u32(s[1][2], s[1][3]);                                    \
        pl32_swap(b0, b2); pl16_swap(b0, b2);                                      \
        pl32_swap(b1, b3); pl16_swap(b1, b3);                                      \
        uint4v pw; pw[0] = b0; pw[1] = b1; pw[2] = b2; pw[3] = b3;                 \
        half8 pf = *(half8*)&pw;                                                   \
        _Pragma("unroll")                                                          \
        for (int cf = 0; cf < 4; cf++) {                                           \
            half8 vf = *(const half8*)(Vc + voff[cf]);                             \
            o[cf] = __builtin_amdgcn_mfma_f32_16x16x32_f16(vf, pf, o[cf], 0, 0, 0); \
        }                                                                          \
        __syncthreads();                                                           \
    }

    for (int t = 0; t < 32; t += 2) {
        ATTN_TILE(0, t);
        ATTN_TILE(1, t + 1);
    }

    lsum += __shfl_xor(lsum, 16, 64);
    lsum += __shfl_xor(lsum, 32, 64);

    float* mo = (float*)smem;             // [64 q][68] padded f32
    float* mml = (float*)(smem + 17408);  // [64 q][2] (m, ls)
    int q2 = qs * 16 + r;
    if (hf) {
#pragma unroll
        for (int cf = 0; cf < 4; cf++)
            *(f32x4*)(mo + q2 * 68 + cf * 16 + g * 4) = o[cf];
        if (l < 16) {
            mml[q2 * 2] = m;
            mml[q2 * 2 + 1] = lsum;
        }
    }
    __syncthreads();
    if (!hf) {
        float m1 = mml[q2 * 2], ls1 = mml[q2 * 2 + 1];
        float M = fmaxf(m, m1);
        float w0 = exp2_fast(m - M), w1 = exp2_fast(m1 - M);
        float inv = 1.0f / (w0 * lsum + w1 * ls1);
        w0 *= inv; w1 *= inv;
        int n = q0 + q2;
        int b = bh >> 4, h = bh & 15;
#pragma unroll
        for (int cf = 0; cf < 4; cf++) {
            f32x4 o1 = *(const f32x4*)(mo + q2 * 68 + cf * 16 + g * 4);
            half4v ov;
#pragma unroll
            for (int e = 0; e < 4; e++) ov[e] = (half_t)(o[cf][e] * w0 + o1[e] * w1);
            *(half4v*)(aoh + ((size_t)b * 2048 + n) * 1024 + h * 64 + cf * 16 + g * 4) = ov;
        }
    }
}

// ---------------- proj GEMM: 64x128 tile, BK=32, dbuf, + bias, f32 out -------------
// PROVEN R16: grid (64,8)=512 blocks -> 2 blocks/CU (8 waves/CU), 24KB LDS.
__global__ __launch_bounds__(256, 4) void gemm_proj(
    const half_t* __restrict__ A, const half_t* __restrict__ Bt,
    const float* __restrict__ bias, float* __restrict__ out) {
    const int K = 1024;
    __shared__ __align__(16) half_t Al[2][64 * 32];
    __shared__ __align__(16) half_t Bl[2][128 * 32];
    int tid = threadIdx.x, w = tid >> 6, l = tid & 63;
    int wr = w >> 1, wc = w & 1, g = l >> 4, r = l & 15;
    int m0 = blockIdx.x * 64, n0 = blockIdx.y * 128;
    f32x4 acc[2][4] = {};

#define STAGE_PROJ(kt, buf)                                                       \
    {                                                                             \
        {                                                                         \
            int ci = tid;                                                         \
            int row = ci >> 2, c = ci & 3, lc = c ^ ((row >> 1) & 3);             \
            gl_lds16(A + (size_t)(m0 + row) * K + (kt) * 32 + lc * 8,             \
                     &Al[buf][0] + ci * 8);                                       \
        }                                                                         \
        _Pragma("unroll")                                                         \
        for (int p = 0; p < 2; p++) {                                             \
            int ci = p * 256 + tid;                                               \
            int row = ci >> 2, c = ci & 3, lc = c ^ ((row >> 1) & 3);             \
            gl_lds16(Bt + (size_t)(n0 + row) * K + (kt) * 32 + lc * 8,            \
                     &Bl[buf][0] + ci * 8);                                       \
        }                                                                         \
    }

    STAGE_PROJ(0, 0);
    __syncthreads();
    int cur = 0;
    for (int kt = 0; kt < 32; kt++) {
        if (kt < 31) STAGE_PROJ(kt + 1, cur ^ 1);
        half8 af[2], bf[4];
#pragma unroll
        for (int i = 0; i < 2; i++) {
            int row = wr * 32 + i * 16 + r;
            af[i] = *(const half8*)(&Al[cur][0] + row * 32 + ((g ^ ((row >> 1) & 3)) << 3));
        }
#pragma unroll
        for (int j = 0; j < 4; j++) {
            int rowb = wc * 64 + j * 16 + r;
            bf[j] = *(const half8*)(&Bl[cur][0] + rowb * 32 + ((g ^ ((rowb >> 1) & 3)) << 3));
        }
#pragma unroll
        for (int i = 0; i < 2; i++)
#pragma unroll
            for (int j = 0; j < 4; j++)
                acc[i][j] = __builtin_amdgcn_mfma_f32_16x16x32_f16(af[i], bf[j], acc[i][j], 0, 0, 0);
        __syncthreads();
        cur ^= 1;
    }

#pragma unroll
    for (int i = 0; i < 2; i++)
#pragma unroll
        for (int j = 0; j < 4; j++) {
            int gcol = n0 + wc * 64 + j * 16 + r;
            float bv = bias[gcol];
#pragma unroll
            for (int rr = 0; rr < 4; rr++) {
                int grow = m0 + wr * 32 + i * 16 + g * 4 + rr;
                out[(size_t)grow * 1024 + gcol] = acc[i][j][rr] + bv;
            }
        }
}

// ---------------- launch ----------------
extern "C" void kernel_launch(void* const* d_in, const int* in_sizes, int n_in,
                              void* d_out, int out_size, void* d_ws, size_t ws_size,
                              hipStream_t stream) {
    const float* x = (const float*)d_in[0];
    const float* Wqkv = (const float*)d_in[1];
    const float* Wproj = (const float*)d_in[2];
    const float* bproj = (const float*)d_in[3];
    const float* qscale = (const float*)d_in[4];
    const float* kscale = (const float*)d_in[5];
    float* out = (float*)d_out;

    char* ws = (char*)d_ws;
    half_t* xh  = (half_t*)(ws + 0);         //  8.0 MB (4096 x 1024 fp16)
    half_t* wqt = (half_t*)(ws + 8388608);   //  6.0 MB (3072 x 1024 fp16, transposed)
    half_t* wpt = (half_t*)(ws + 14680064);  //  2.0 MB (1024 x 1024 fp16, transposed)
    half_t* qh  = (half_t*)(ws + 16777216);  //  8.0 MB (b,h,n,f)
    half_t* kh  = (half_t*)(ws + 25165824);  //  8.0 MB (b,h,n,f)
    half_t* vth = (half_t*)(ws + 33554432);  //  8.0 MB (b,h,f,n)
    half_t* aoh = (half_t*)(ws + 41943040);  //  8.0 MB (b,n,c)

    prep_all<<<8192, 256, 0, stream>>>(x, Wqkv, Wproj, xh, wqt, wpt);
    gemm_qkv<<<dim3(32, 24), 256, 0, stream>>>(xh, wqt, qscale, kscale, qh, kh, vth);
    attn<<<dim3(32, 32), 512, 0, stream>>>(qh, kh, vth, aoh);
    gemm_proj<<<dim3(64, 8), 256, 0, stream>>>(aoh, wpt, bproj, out);
}